// Round 11
// baseline (413.913 us; speedup 1.0000x reference)
//
#include <hip/hip_runtime.h>

// ---------------------------------------------------------------------------
// BoringAttention (talking-heads) on MI355X.
// Pipeline:
//   conv_bf16   : x fp32 -> xb bf16
//   transW x2   : Wq|Wkv -> WbT [3072][1024] bf16
//   gemm_bt     : xb @ W -> qkv bf16 [4096][3072]  [reg-staged 128^2, r8 best]
//   fill_K      : K_ws [b][h][2064][64] bf16 (mem_k prepended)
//   fill_Vt     : Vt_ws [b][h][64][2064] bf16 (transposed, mem_v prepended)
//   memset      : O_ws (fp32), l_ws (fp32)
//   attn_stats  : i-tile 64, j-chunk 160, 2-barrier round (r8 best) + SKIP
//   attn_av     : i-tile 32, j-chunk 160, FUSED premix->postmix (shfl) + SKIP
// ROUND-11: (a) revert attn_stats to r8's i-tile-64 2-barrier version (r10's
// 1-barrier pipelined round was -5us: intra-block pipelining keeps losing to
// the simple structure + 2-blk/CU implicit overlap — 3rd confirmation).
// (b) causal-group skip: premix groups with j0+jt*16 > i0+ii+16 are FULLY
// masked; condition is wave-uniform -> whole wave branches around the
// premix MFMA (+exp in stats; +shfl+postmix in av). av must write ZEROS to
// Pp for skipped groups (stale Pp would feed AV). ~10% of frontier u-iters.
// Falsified levers (do not retry): XCD swizzle for atomics (r5: atomics are
// memory-side), chunk-size traffic cuts (r6), i-tile occupancy trades (r2),
// launch_bounds min-waves on 1024-thr blocks (r7: spill 2.5x),
// global_load_lds for this GEMM shape (r9), 1-barrier attn rounds (r1/r10).
// ---------------------------------------------------------------------------

typedef __attribute__((ext_vector_type(8))) short short8;
typedef __attribute__((ext_vector_type(4))) float floatx4;

#define MFMA16(a, b, c) __builtin_amdgcn_mfma_f32_16x16x32_bf16(a, b, c, 0, 0, 0)
// LDS-only barrier: do NOT drain vmcnt (keeps K/V prefetch in flight).
#define BARLDS() __asm__ volatile("s_waitcnt lgkmcnt(0)\n\ts_barrier" ::: "memory")

static __device__ __forceinline__ unsigned short f2bf(float f) {
  union { float f; unsigned u; } v; v.f = f;
  unsigned r = v.u + 0x7fffu + ((v.u >> 16) & 1u);
  return (unsigned short)(r >> 16);
}
static __device__ __forceinline__ float bf2f(unsigned short h) {
  union { unsigned u; float f; } v; v.u = ((unsigned)h) << 16;
  return v.f;
}

union S8U { short8 v; unsigned short u[8]; };

// ---------------- fp32 -> bf16 elementwise (8 elems/thread) -----------------
__global__ __launch_bounds__(256) void conv_bf16(const float* __restrict__ src,
                                                 unsigned short* __restrict__ dst,
                                                 int n8) {
  int tid = blockIdx.x * 256 + threadIdx.x;
  if (tid >= n8) return;
  const float4* s = (const float4*)src + (size_t)tid * 2;
  float4 a = s[0], b = s[1];
  S8U o;
  o.u[0] = f2bf(a.x); o.u[1] = f2bf(a.y); o.u[2] = f2bf(a.z); o.u[3] = f2bf(a.w);
  o.u[4] = f2bf(b.x); o.u[5] = f2bf(b.y); o.u[6] = f2bf(b.z); o.u[7] = f2bf(b.w);
  *(short8*)(dst + (size_t)tid * 8) = o.v;
}

// ---------------- transpose-convert W [K=1024][N] -> dst[N][1024] bf16 ------
__global__ __launch_bounds__(256) void transW(const float* __restrict__ src, int Ncols,
                                              unsigned short* __restrict__ dst, int dstRowOff) {
  __shared__ float sw[32][33];
  int n0 = blockIdx.x * 32, k0 = blockIdx.y * 32;
  int t = threadIdx.x;
  int lk = t >> 3, n4 = (t & 7) * 4;
  const float* s = src + (size_t)(k0 + lk) * Ncols + n0 + n4;
  sw[lk][n4 + 0] = s[0]; sw[lk][n4 + 1] = s[1];
  sw[lk][n4 + 2] = s[2]; sw[lk][n4 + 3] = s[3];
  __syncthreads();
  int ln = t >> 3, k4 = (t & 7) * 4;
  unsigned o0 = f2bf(sw[k4 + 0][ln]) | ((unsigned)f2bf(sw[k4 + 1][ln]) << 16);
  unsigned o1 = f2bf(sw[k4 + 2][ln]) | ((unsigned)f2bf(sw[k4 + 3][ln]) << 16);
  uint2 pk; pk.x = o0; pk.y = o1;
  *(uint2*)(dst + (size_t)(dstRowOff + n0 + ln) * 1024 + k0 + k4) = pk;
}

// ---------------- bf16 MFMA GEMM, LDS-staged 128x128 tile (r8 best) ---------
__global__ __launch_bounds__(256) void gemm_bt(const unsigned short* __restrict__ A,
                                               const unsigned short* __restrict__ BT,
                                               unsigned short* __restrict__ Cb,
                                               float* __restrict__ Cf,
                                               int M, int N, int K, int f32out) {
  __shared__ unsigned short Al[128 * 40];
  __shared__ unsigned short Bl[128 * 40];
  const int t = threadIdx.x;
  const int w = t >> 6, lane = t & 63;
  const int quad = lane >> 4, l16 = lane & 15;
  const int mb = blockIdx.x * 128, nb = blockIdx.y * 128;
  const int m0 = (w >> 1) * 64, n0 = (w & 1) * 64;
  const int srow = t >> 1, scol = (t & 1) * 16;
  const unsigned short* Ag = A + (size_t)(mb + srow) * K + scol;
  const unsigned short* Bg = BT + (size_t)(nb + srow) * K + scol;
  unsigned short* Aw = Al + srow * 40 + scol;
  unsigned short* Bw = Bl + srow * 40 + scol;

  floatx4 acc[4][4];
#pragma unroll
  for (int i = 0; i < 4; i++)
#pragma unroll
    for (int j = 0; j < 4; j++) acc[i][j] = (floatx4){0.f, 0.f, 0.f, 0.f};

  short8 a0 = *(const short8*)(Ag);
  short8 a1 = *(const short8*)(Ag + 8);
  short8 b0 = *(const short8*)(Bg);
  short8 b1 = *(const short8*)(Bg + 8);

  for (int kk = 0; kk < K; kk += 32) {
    __syncthreads();
    *(short8*)(Aw) = a0; *(short8*)(Aw + 8) = a1;
    *(short8*)(Bw) = b0; *(short8*)(Bw + 8) = b1;
    __syncthreads();
    if (kk + 32 < K) {
      a0 = *(const short8*)(Ag + kk + 32);
      a1 = *(const short8*)(Ag + kk + 40);
      b0 = *(const short8*)(Bg + kk + 32);
      b1 = *(const short8*)(Bg + kk + 40);
    }
    short8 af[4], bf[4];
#pragma unroll
    for (int s = 0; s < 4; s++) {
      af[s] = *(const short8*)(Al + (m0 + s * 16 + l16) * 40 + quad * 8);
      bf[s] = *(const short8*)(Bl + (n0 + s * 16 + l16) * 40 + quad * 8);
    }
#pragma unroll
    for (int mt = 0; mt < 4; mt++)
#pragma unroll
      for (int nt = 0; nt < 4; nt++) acc[mt][nt] = MFMA16(af[mt], bf[nt], acc[mt][nt]);
  }
#pragma unroll
  for (int mt = 0; mt < 4; mt++)
#pragma unroll
    for (int nt = 0; nt < 4; nt++)
#pragma unroll
      for (int r = 0; r < 4; r++) {
        size_t row = mb + m0 + mt * 16 + quad * 4 + r;
        size_t col = nb + n0 + nt * 16 + l16;
        if (f32out) Cf[row * N + col] = acc[mt][nt][r];
        else Cb[row * N + col] = f2bf(acc[mt][nt][r]);
      }
}

// ---------------- build K_ws [b][h][2064][64] bf16 --------------------------
__global__ __launch_bounds__(256) void fill_K(const unsigned short* __restrict__ qkv,
                                              const float* __restrict__ mem_k,
                                              unsigned short* __restrict__ Kw) {
  int tid = blockIdx.x * 256 + threadIdx.x;
  if (tid >= 2 * 16 * 2064 * 8) return;
  int d0 = (tid & 7) * 8;
  int j = (tid >> 3) % 2064;
  int h = ((tid >> 3) / 2064) & 15;
  int b = (tid >> 3) / (2064 * 16);
  S8U o;
  if (j < 16) {
    const float* s = mem_k + ((size_t)(h * 16 + j) * 64 + d0);
#pragma unroll
    for (int c = 0; c < 8; c++) o.u[c] = f2bf(s[c]);
  } else {
    o.v = *(const short8*)(qkv + (size_t)(b * 2048 + j - 16) * 3072 + 1024 + h * 64 + d0);
  }
  *(short8*)(Kw + ((size_t)(b * 16 + h) * 2064 + j) * 64 + d0) = o.v;
}

// ---------------- build Vt_ws [b][h][64][2064] bf16 (transposed) ------------
__global__ __launch_bounds__(256) void fill_Vt(const unsigned short* __restrict__ qkv,
                                               const float* __restrict__ mem_v,
                                               unsigned short* __restrict__ Vt) {
  __shared__ float sv[16][65];
  int jt = blockIdx.x, h = blockIdx.y, b = blockIdx.z;
  int t = threadIdx.x;
  int j = t >> 4, d0 = (t & 15) * 4;
  int jg = jt * 16 + j;
  float v0, v1, v2, v3;
  if (jg < 16) {
    const float* s = mem_v + ((size_t)(h * 16 + jg) * 64 + d0);
    v0 = s[0]; v1 = s[1]; v2 = s[2]; v3 = s[3];
  } else {
    const unsigned short* s = qkv + (size_t)(b * 2048 + jg - 16) * 3072 + 2048 + h * 64 + d0;
    v0 = bf2f(s[0]); v1 = bf2f(s[1]); v2 = bf2f(s[2]); v3 = bf2f(s[3]);
  }
  sv[j][d0 + 0] = v0; sv[j][d0 + 1] = v1; sv[j][d0 + 2] = v2; sv[j][d0 + 3] = v3;
  __syncthreads();
  int d = t >> 2, j4 = (t & 3) * 4;
  unsigned o0 = f2bf(sv[j4 + 0][d]) | ((unsigned)f2bf(sv[j4 + 1][d]) << 16);
  unsigned o1 = f2bf(sv[j4 + 2][d]) | ((unsigned)f2bf(sv[j4 + 3][d]) << 16);
  uint2 pk; pk.x = o0; pk.y = o1;
  *(uint2*)(Vt + ((size_t)(b * 16 + h) * 64 + d) * 2064 + jt * 16 + j4) = pk;
}

// ---------------------------------------------------------------------------
// attn_stats: l[b,i,k'] = sum over causal j of exp(S'[k',i,j]).
// Grid (c<13, it<32, b<2), 16 waves. i-tile 64, j-chunk 160, j-round 32.
// Dense S rows: addr = i*520 + j*16 + h; S = 66,560 B. 2-barrier round.
// Wave w: QK head h=w (all 64 i); pre-mix + exp for rows i* = 4w..4w+3.
// Causal-group skip: u-iter groups with j0+jt*16 > i0+ii+16 are fully
// masked -> wave-uniform branch skips premix MFMA + exp entirely.
// ---------------------------------------------------------------------------
__global__ __launch_bounds__(1024) void attn_stats(const unsigned short* __restrict__ qkv,
                                                   const unsigned short* __restrict__ Kw,
                                                   const float* __restrict__ pre,
                                                   float* __restrict__ l_ws) {
  const int c = blockIdx.x, it = blockIdx.y, b = blockIdx.z;
  const int i0 = it * 64;
  const int jmax = i0 + 80;          // exclusive causal bound (j <= i+16)
  const int jc0 = c * 160;
  if (jc0 >= jmax) return;
  const int jend = min(jmax, jc0 + 160);
  const int niter = (jend - jc0 + 31) >> 5;

  __shared__ unsigned short S_lds[64 * 520];  // 66,560 B

  const int tid = threadIdx.x, w = tid >> 6, lane = tid & 63;
  const int quad = lane >> 4, l16 = lane & 15;
  const int hoff = (quad < 2) ? quad * 8 : 0;

  short8 qa[4][2];
#pragma unroll
  for (int s = 0; s < 4; s++) {
    const unsigned short* p =
        qkv + (size_t)(b * 2048 + i0 + s * 16 + l16) * 3072 + w * 64 + quad * 8;
    qa[s][0] = *(const short8*)p;
    qa[s][1] = *(const short8*)(p + 32);
  }
  short8 preA;
#pragma unroll
  for (int jj = 0; jj < 8; jj++) {
    int h = quad * 8 + jj;
    preA[jj] = (short)((quad < 2) ? f2bf(pre[h * 16 + l16] * 0.125f) : 0);
  }
  const unsigned short* Kb = Kw + (size_t)(b * 16 + w) * 2064 * 64;

  float l_loc[4][4];
#pragma unroll
  for (int i4 = 0; i4 < 4; i4++)
#pragma unroll
    for (int r = 0; r < 4; r++) l_loc[i4][r] = 0.f;

  // K register prefetch: preload round 0
  short8 kf[2][2];
#pragma unroll
  for (int jt = 0; jt < 2; jt++) {
    int jr = min(jc0 + jt * 16 + l16, 2063);
    const unsigned short* kp = Kb + (size_t)jr * 64 + quad * 8;
    kf[jt][0] = *(const short8*)kp;
    kf[jt][1] = *(const short8*)(kp + 32);
  }

  for (int n = 0; n < niter; n++) {
    const int j0 = jc0 + n * 32;
    // ---- QK^T -> S_lds (bf16) ----
#pragma unroll
    for (int jt = 0; jt < 2; jt++)
#pragma unroll
      for (int s = 0; s < 4; s++) {
        floatx4 a = (floatx4){0.f, 0.f, 0.f, 0.f};
        a = MFMA16(qa[s][0], kf[jt][0], a);
        a = MFMA16(qa[s][1], kf[jt][1], a);
#pragma unroll
        for (int r = 0; r < 4; r++)
          S_lds[(s * 16 + quad * 4 + r) * 520 + (jt * 16 + l16) * 16 + w] = f2bf(a[r]);
      }
    // ---- prefetch next round's K (stays in flight across barriers) ----
    if (n + 1 < niter) {
      const int j0n = j0 + 32;
#pragma unroll
      for (int jt = 0; jt < 2; jt++) {
        int jr = min(j0n + jt * 16 + l16, 2063);
        const unsigned short* kp = Kb + (size_t)jr * 64 + quad * 8;
        kf[jt][0] = *(const short8*)kp;
        kf[jt][1] = *(const short8*)(kp + 32);
      }
    }
    BARLDS();
    // ---- pre-mix (16x16x32, zero-padded K) + exp accumulate ----
#pragma unroll
    for (int u = 0; u < 8; u++) {
      const int iloc = u >> 1, jt = u & 1, ii = w * 4 + iloc;
      // wave-uniform causal-group skip: whole 16-j group beyond frontier
      if (j0 + jt * 16 > i0 + ii + 16) continue;
      const short8 bb = *(const short8*)(S_lds + ii * 520 + (jt * 16 + l16) * 16 + hoff);
      floatx4 sp = (floatx4){0.f, 0.f, 0.f, 0.f};
      sp = MFMA16(preA, bb, sp);
      const int jg = j0 + jt * 16 + l16;
      if (jg <= i0 + ii + 16) {
#pragma unroll
        for (int r = 0; r < 4; r++) l_loc[iloc][r] += __expf(sp[r]);
      }
    }
    if (n + 1 < niter) BARLDS();
  }
#pragma unroll
  for (int iloc = 0; iloc < 4; iloc++)
#pragma unroll
    for (int r = 0; r < 4; r++) {
      float v = l_loc[iloc][r];
      v += __shfl_xor(v, 1);
      v += __shfl_xor(v, 2);
      v += __shfl_xor(v, 4);
      v += __shfl_xor(v, 8);
      if (l16 == 0)
        atomicAdd(l_ws + ((size_t)(b * 2048 + i0 + w * 4 + iloc) * 16 + quad * 4 + r), v);
    }
}

// ---------------------------------------------------------------------------
// attn_av: recompute S', P=exp(S')/l, post-mix, AV; atomicAdd O_ws fp32.
// Grid (c<13, it<64, b<2), 16 waves, i-tile 32, j-chunk 160 (r4 best).
// FUSED premix->postmix via shfl (r8): P never touches LDS. Premix C-frag
// lane(quad,l16) reg r = P(k'=quad*4+r, j=l16); postmix B-frag needs
// lane(q,l16) to hold k'=q*8..q*8+7 at its j -> pack bf16 pairs, 4 __shfl
// from lanes quad*32+l16 / +16 (k'>=16 half zero-padded via postA).
// Causal-group skip: fully-masked groups write ZEROS to Pp (stale Pp would
// feed AV) and skip premix MFMA + exp + shfl + postmix; wave-uniform branch.
// Dense S rows: S 33,280 B + Pp 41,216 B = 74,496 B. Wave w: QK head h=w;
// mixes rows i* = 2w..2w+1; AV value head k2=w. Plain launch_bounds(1024):
// allocator lands at 64 VGPR (r8); forcing min-waves spills (r7).
// ---------------------------------------------------------------------------
__global__ __launch_bounds__(1024) void attn_av(const unsigned short* __restrict__ qkv,
                                                const unsigned short* __restrict__ Kw,
                                                const unsigned short* __restrict__ Vt,
                                                const float* __restrict__ pre,
                                                const float* __restrict__ post,
                                                const float* __restrict__ l_ws,
                                                float* __restrict__ O_ws) {
  const int c = blockIdx.x, it = blockIdx.y, b = blockIdx.z;
  const int i0 = it * 32;
  const int jmax = i0 + 48;
  const int jc0 = c * 160;
  if (jc0 >= jmax) return;
  const int jend = min(jmax, jc0 + 160);
  const int niter = (jend - jc0 + 31) >> 5;

  __shared__ unsigned short S_lds[32 * 520];    // 33,280 B (QK output only)
  __shared__ unsigned short Pp_lds[16 * 1288];  // 41,216 B

  const int tid = threadIdx.x, w = tid >> 6, lane = tid & 63;
  const int quad = lane >> 4, l16 = lane & 15;
  const int hoff = (quad < 2) ? quad * 8 : 0;
  const int srcA = (quad * 32 + l16) & 63;      // shfl srcs for P regather
  const int srcB = (srcA + 16) & 63;

  short8 qa[2][2];
#pragma unroll
  for (int s = 0; s < 2; s++) {
    const unsigned short* p =
        qkv + (size_t)(b * 2048 + i0 + s * 16 + l16) * 3072 + w * 64 + quad * 8;
    qa[s][0] = *(const short8*)p;
    qa[s][1] = *(const short8*)(p + 32);
  }
  short8 preA, postA;
#pragma unroll
  for (int jj = 0; jj < 8; jj++) {
    int h = quad * 8 + jj;
    float pv = 0.f, qv = 0.f;
    if (quad < 2) { pv = pre[h * 16 + l16] * 0.125f; qv = post[h * 16 + l16]; }
    preA[jj] = (short)f2bf(pv);
    postA[jj] = (short)f2bf(qv);
  }
  float rl[2][4];
#pragma unroll
  for (int iloc = 0; iloc < 2; iloc++)
#pragma unroll
    for (int r = 0; r < 4; r++)
      rl[iloc][r] = 1.0f / l_ws[(size_t)(b * 2048 + i0 + w * 2 + iloc) * 16 + quad * 4 + r];

  floatx4 oacc[2][4];
#pragma unroll
  for (int g = 0; g < 2; g++)
#pragma unroll
    for (int d = 0; d < 4; d++) oacc[g][d] = (floatx4){0.f, 0.f, 0.f, 0.f};

  const unsigned short* Kb = Kw + (size_t)(b * 16 + w) * 2064 * 64;
  const unsigned short* Vb = Vt + (size_t)(b * 16 + w) * 64 * 2064;

  short8 kf[2][2];
#pragma unroll
  for (int jt = 0; jt < 2; jt++) {
    int jr = min(jc0 + jt * 16 + l16, 2063);
    const unsigned short* kp = Kb + (size_t)jr * 64 + quad * 8;
    kf[jt][0] = *(const short8*)kp;
    kf[jt][1] = *(const short8*)(kp + 32);
  }

  for (int n = 0; n < niter; n++) {
    const int j0 = jc0 + n * 32;
    // ---- V fragments for this iteration (independent; issues early) ----
    short8 vf[4];
    {
      const int jc = min(j0 + quad * 8, 2056);
#pragma unroll
      for (int d = 0; d < 4; d++)
        vf[d] = *(const short8*)(Vb + (size_t)(d * 16 + l16) * 2064 + jc);
    }
    // ---- QK^T -> S_lds ----
#pragma unroll
    for (int jt = 0; jt < 2; jt++)
#pragma unroll
      for (int s = 0; s < 2; s++) {
        floatx4 a = (floatx4){0.f, 0.f, 0.f, 0.f};
        a = MFMA16(qa[s][0], kf[jt][0], a);
        a = MFMA16(qa[s][1], kf[jt][1], a);
#pragma unroll
        for (int r = 0; r < 4; r++)
          S_lds[(s * 16 + quad * 4 + r) * 520 + (jt * 16 + l16) * 16 + w] = f2bf(a[r]);
      }
    // ---- prefetch next K ----
    if (n + 1 < niter) {
      const int j0n = j0 + 32;
#pragma unroll
      for (int jt = 0; jt < 2; jt++) {
        int jr = min(j0n + jt * 16 + l16, 2063);
        const unsigned short* kp = Kb + (size_t)jr * 64 + quad * 8;
        kf[jt][0] = *(const short8*)kp;
        kf[jt][1] = *(const short8*)(kp + 32);
      }
    }
    BARLDS();
    // ---- fused: pre-mix + exp/l -> P (regs) -> shfl regather -> post-mix ----
#pragma unroll
    for (int u = 0; u < 4; u++) {
      const int iloc = u >> 1, jt = u & 1, ii = w * 2 + iloc;
      // wave-uniform causal-group skip: fully-masked -> Pp must be ZERO
      if (j0 + jt * 16 > i0 + ii + 16) {
#pragma unroll
        for (int r = 0; r < 4; r++)
          Pp_lds[(quad * 4 + r) * 1288 + ii * 40 + jt * 16 + l16] = 0;
        continue;
      }
      const int sc = ii * 520 + (jt * 16 + l16) * 16;
      const short8 bb = *(const short8*)(S_lds + sc + hoff);
      floatx4 sp = (floatx4){0.f, 0.f, 0.f, 0.f};
      sp = MFMA16(preA, bb, sp);
      const int jg = j0 + jt * 16 + l16;
      const bool keep = jg <= (i0 + ii + 16);
      float p0 = keep ? __expf(sp[0]) * rl[iloc][0] : 0.f;
      float p1 = keep ? __expf(sp[1]) * rl[iloc][1] : 0.f;
      float p2 = keep ? __expf(sp[2]) * rl[iloc][2] : 0.f;
      float p3 = keep ? __expf(sp[3]) * rl[iloc][3] : 0.f;
      // pack P(k=quad*4+{0,1}) and (quad*4+{2,3}) as bf16 word-pairs
      unsigned w01 = (unsigned)f2bf(p0) | ((unsigned)f2bf(p1) << 16);
      unsigned w23 = (unsigned)f2bf(p2) | ((unsigned)f2bf(p3) << 16);
      // regather to postmix B-frag: lane (q,l16) needs k = q*8..q*8+7 at its j
      union { unsigned u32[4]; short8 v; } pfu;
      pfu.u32[0] = __shfl(w01, srcA, 64);
      pfu.u32[1] = __shfl(w23, srcA, 64);
      pfu.u32[2] = __shfl(w01, srcB, 64);
      pfu.u32[3] = __shfl(w23, srcB, 64);
      floatx4 pp = (floatx4){0.f, 0.f, 0.f, 0.f};
      pp = MFMA16(postA, pfu.v, pp);
#pragma unroll
      for (int r = 0; r < 4; r++)
        Pp_lds[(quad * 4 + r) * 1288 + ii * 40 + jt * 16 + l16] = f2bf(pp[r]);
    }
    BARLDS();
    // ---- AV: wave w = value head k2=w, K = 32 j's ----
#pragma unroll
    for (int g = 0; g < 2; g++) {
      const short8 paf = *(const short8*)(Pp_lds + w * 1288 + (g * 16 + l16) * 40 + quad * 8);
#pragma unroll
      for (int d = 0; d < 4; d++) oacc[g][d] = MFMA16(paf, vf[d], oacc[g][d]);
    }
  }
  // ---- accumulate into O_ws fp32 ----
#pragma unroll
  for (int g = 0; g < 2; g++)
#pragma unroll
    for (int d = 0; d < 4; d++)
#pragma unroll
      for (int r = 0; r < 4; r++)
        atomicAdd(O_ws + (size_t)(b * 2048 + i0 + g * 16 + quad * 4 + r) * 1024 +
                      w * 64 + d * 16 + l16,
                  oacc[g][d][r]);
}

// ---------------------------------------------------------------------------
extern "C" void kernel_launch(void* const* d_in, const int* in_sizes, int n_in,
                              void* d_out, int out_size, void* d_ws, size_t ws_size,
                              hipStream_t stream) {
  (void)in_sizes; (void)n_in; (void)out_size; (void)ws_size;
  const float* x     = (const float*)d_in[0];
  const float* Wq    = (const float*)d_in[1];
  const float* Wkv   = (const float*)d_in[2];
  const float* Wo    = (const float*)d_in[3];
  const float* pre   = (const float*)d_in[4];
  const float* post  = (const float*)d_in[5];
  const float* mem_k = (const float*)d_in[6];
  const float* mem_v = (const float*)d_in[7];
  float* out = (float*)d_out;
  char* ws = (char*)d_ws;

  // Temporally-aliased workspace (total 67,239,936 B):
  //   [0, 16.8M):  xb(8M)+WbT(6M)+pad — dead after qkv gemm -> O_ws fp32 16M
  //   [16.8M, 41.9M): qkv bf16 — dead after attn_av -> WoT (2M)
  //   [41.9M, 50.4M): Kw ; [50.4M, 58.9M): Vt
  //   [58.9M, 67.2M): l_ws (256K, dead after attn_av) then attn_b bf16 (8M)
  unsigned short* xb     = (unsigned short*)(ws);
  unsigned short* WbT    = (unsigned short*)(ws + 8388608);
  float*          O_ws   = (float*)(ws);                     // 16,777,216 B
  unsigned short* qkv    = (unsigned short*)(ws + 16777216); // 25,165,824 B
  unsigned short* WoT    = (unsigned short*)(ws + 16777216); // 2 MB (post-attn)
  unsigned short* Kw     = (unsigned short*)(ws + 41943040); //  8,454,144 B
  unsigned short* Vt     = (unsigned short*)(ws + 50397184); //  8,454,144 B
  float*          l_ws   = (float*)(ws + 58851328);          //    262,144 B
  unsigned short* attn_b = (unsigned short*)(ws + 58851328); //  8,388,608 B

  conv_bf16<<<2048, 256, 0, stream>>>(x, xb, 524288);
  transW<<<dim3(32, 32), 256, 0, stream>>>(Wq, 1024, WbT, 0);
  transW<<<dim3(64, 32), 256, 0, stream>>>(Wkv, 2048, WbT, 1024);
  gemm_bt<<<dim3(32, 24), 256, 0, stream>>>(xb, WbT, qkv, nullptr, 4096, 3072, 1024, 0);
  fill_K<<<2064, 256, 0, stream>>>(qkv, mem_k, Kw);
  fill_Vt<<<dim3(129, 16, 2), 256, 0, stream>>>(qkv, mem_v, Vt);
  hipMemsetAsync(O_ws, 0, 16777216, stream);   // xb/WbT dead now
  hipMemsetAsync(l_ws, 0, 262144, stream);
  attn_stats<<<dim3(13, 32, 2), 1024, 0, stream>>>(qkv, Kw, pre, l_ws);
  attn_av<<<dim3(13, 64, 2), 1024, 0, stream>>>(qkv, Kw, Vt, pre, post, l_ws, O_ws);
  conv_bf16<<<2048, 256, 0, stream>>>(O_ws, attn_b, 524288);  // l_ws dead now
  transW<<<dim3(32, 32), 256, 0, stream>>>(Wo, 1024, WoT, 0); // qkv dead now
  gemm_bt<<<dim3(32, 8), 256, 0, stream>>>(attn_b, WoT, nullptr, out, 4096, 1024, 1024, 1);
}

// Round 12
// 400.415 us; speedup vs baseline: 1.0337x; 1.0337x over previous
//
#include <hip/hip_runtime.h>

// ---------------------------------------------------------------------------
// BoringAttention (talking-heads) on MI355X.  [r12 = exact r8 revert, the
// session's measured-best configuration: 401.4 us]
// Pipeline:
//   conv_bf16   : x fp32 -> xb bf16
//   transW x2   : Wq|Wkv -> WbT [3072][1024] bf16
//   gemm_bt     : xb @ W -> qkv bf16 [4096][3072]  [reg-staged 128^2, r8 best]
//   fill_K      : K_ws [b][h][2064][64] bf16 (mem_k prepended)
//   fill_Vt     : Vt_ws [b][h][64][2064] bf16 (transposed, mem_v prepended)
//   memset      : O_ws (fp32), l_ws (fp32)
//   attn_stats  : i-tile 64, j-chunk 160, 2-barrier round (r8 best)
//   attn_av     : i-tile 32, j-chunk 160, FUSED premix->postmix (shfl) [r8]
// Complete falsified-lever ledger (do not retry):
//   r1/r10: 1-barrier pipelined attn rounds (implicit 2-blk/CU wave overlap
//           already captures it; explicit pipelining loses 3x tested)
//   r2:     smaller i-tile for occupancy (round count doubles, traffic up)
//   r5:     XCD swizzle for atomics (WRITE byte-identical -> fp32 atomics
//           execute memory-side, placement irrelevant)
//   r6:     bigger j-chunks to cut atomic traffic (-45% bytes, +10% dur:
//           latency-bound, not traffic-bound)
//   r7:     launch_bounds min-waves on 1024-thr blocks (forced 32 VGPR,
//           catastrophic spill, 2.5x)
//   r9:     global_load_lds for this GEMM (linear LDS -> 8-way frag-read
//           conflicts beat the DMA savings at K=1024)
//   r11:    causal-group skip (runtime branch in unrolled loop defeats
//           dense scheduling: +11us despite -10% MFMA work)
// Proven wins: r3 GEMM LDS staging (+70us), r8 P-fusion via shfl (+21us).
// Grids dim3(c, it, b), c FASTEST (r1: losing dispatch adjacency costs
// +466MB WRITE). Raw s_barrier drains lgkmcnt only (K/V prefetch in flight).
// ---------------------------------------------------------------------------

typedef __attribute__((ext_vector_type(8))) short short8;
typedef __attribute__((ext_vector_type(4))) float floatx4;

#define MFMA16(a, b, c) __builtin_amdgcn_mfma_f32_16x16x32_bf16(a, b, c, 0, 0, 0)
// LDS-only barrier: do NOT drain vmcnt (keeps K/V prefetch in flight).
#define BARLDS() __asm__ volatile("s_waitcnt lgkmcnt(0)\n\ts_barrier" ::: "memory")

static __device__ __forceinline__ unsigned short f2bf(float f) {
  union { float f; unsigned u; } v; v.f = f;
  unsigned r = v.u + 0x7fffu + ((v.u >> 16) & 1u);
  return (unsigned short)(r >> 16);
}
static __device__ __forceinline__ float bf2f(unsigned short h) {
  union { unsigned u; float f; } v; v.u = ((unsigned)h) << 16;
  return v.f;
}

union S8U { short8 v; unsigned short u[8]; };

// ---------------- fp32 -> bf16 elementwise (8 elems/thread) -----------------
__global__ __launch_bounds__(256) void conv_bf16(const float* __restrict__ src,
                                                 unsigned short* __restrict__ dst,
                                                 int n8) {
  int tid = blockIdx.x * 256 + threadIdx.x;
  if (tid >= n8) return;
  const float4* s = (const float4*)src + (size_t)tid * 2;
  float4 a = s[0], b = s[1];
  S8U o;
  o.u[0] = f2bf(a.x); o.u[1] = f2bf(a.y); o.u[2] = f2bf(a.z); o.u[3] = f2bf(a.w);
  o.u[4] = f2bf(b.x); o.u[5] = f2bf(b.y); o.u[6] = f2bf(b.z); o.u[7] = f2bf(b.w);
  *(short8*)(dst + (size_t)tid * 8) = o.v;
}

// ---------------- transpose-convert W [K=1024][N] -> dst[N][1024] bf16 ------
__global__ __launch_bounds__(256) void transW(const float* __restrict__ src, int Ncols,
                                              unsigned short* __restrict__ dst, int dstRowOff) {
  __shared__ float sw[32][33];
  int n0 = blockIdx.x * 32, k0 = blockIdx.y * 32;
  int t = threadIdx.x;
  int lk = t >> 3, n4 = (t & 7) * 4;
  const float* s = src + (size_t)(k0 + lk) * Ncols + n0 + n4;
  sw[lk][n4 + 0] = s[0]; sw[lk][n4 + 1] = s[1];
  sw[lk][n4 + 2] = s[2]; sw[lk][n4 + 3] = s[3];
  __syncthreads();
  int ln = t >> 3, k4 = (t & 7) * 4;
  unsigned o0 = f2bf(sw[k4 + 0][ln]) | ((unsigned)f2bf(sw[k4 + 1][ln]) << 16);
  unsigned o1 = f2bf(sw[k4 + 2][ln]) | ((unsigned)f2bf(sw[k4 + 3][ln]) << 16);
  uint2 pk; pk.x = o0; pk.y = o1;
  *(uint2*)(dst + (size_t)(dstRowOff + n0 + ln) * 1024 + k0 + k4) = pk;
}

// ---------------- bf16 MFMA GEMM, LDS-staged 128x128 tile (r8 best) ---------
__global__ __launch_bounds__(256) void gemm_bt(const unsigned short* __restrict__ A,
                                               const unsigned short* __restrict__ BT,
                                               unsigned short* __restrict__ Cb,
                                               float* __restrict__ Cf,
                                               int M, int N, int K, int f32out) {
  __shared__ unsigned short Al[128 * 40];
  __shared__ unsigned short Bl[128 * 40];
  const int t = threadIdx.x;
  const int w = t >> 6, lane = t & 63;
  const int quad = lane >> 4, l16 = lane & 15;
  const int mb = blockIdx.x * 128, nb = blockIdx.y * 128;
  const int m0 = (w >> 1) * 64, n0 = (w & 1) * 64;
  const int srow = t >> 1, scol = (t & 1) * 16;
  const unsigned short* Ag = A + (size_t)(mb + srow) * K + scol;
  const unsigned short* Bg = BT + (size_t)(nb + srow) * K + scol;
  unsigned short* Aw = Al + srow * 40 + scol;
  unsigned short* Bw = Bl + srow * 40 + scol;

  floatx4 acc[4][4];
#pragma unroll
  for (int i = 0; i < 4; i++)
#pragma unroll
    for (int j = 0; j < 4; j++) acc[i][j] = (floatx4){0.f, 0.f, 0.f, 0.f};

  short8 a0 = *(const short8*)(Ag);
  short8 a1 = *(const short8*)(Ag + 8);
  short8 b0 = *(const short8*)(Bg);
  short8 b1 = *(const short8*)(Bg + 8);

  for (int kk = 0; kk < K; kk += 32) {
    __syncthreads();
    *(short8*)(Aw) = a0; *(short8*)(Aw + 8) = a1;
    *(short8*)(Bw) = b0; *(short8*)(Bw + 8) = b1;
    __syncthreads();
    if (kk + 32 < K) {
      a0 = *(const short8*)(Ag + kk + 32);
      a1 = *(const short8*)(Ag + kk + 40);
      b0 = *(const short8*)(Bg + kk + 32);
      b1 = *(const short8*)(Bg + kk + 40);
    }
    short8 af[4], bf[4];
#pragma unroll
    for (int s = 0; s < 4; s++) {
      af[s] = *(const short8*)(Al + (m0 + s * 16 + l16) * 40 + quad * 8);
      bf[s] = *(const short8*)(Bl + (n0 + s * 16 + l16) * 40 + quad * 8);
    }
#pragma unroll
    for (int mt = 0; mt < 4; mt++)
#pragma unroll
      for (int nt = 0; nt < 4; nt++) acc[mt][nt] = MFMA16(af[mt], bf[nt], acc[mt][nt]);
  }
#pragma unroll
  for (int mt = 0; mt < 4; mt++)
#pragma unroll
    for (int nt = 0; nt < 4; nt++)
#pragma unroll
      for (int r = 0; r < 4; r++) {
        size_t row = mb + m0 + mt * 16 + quad * 4 + r;
        size_t col = nb + n0 + nt * 16 + l16;
        if (f32out) Cf[row * N + col] = acc[mt][nt][r];
        else Cb[row * N + col] = f2bf(acc[mt][nt][r]);
      }
}

// ---------------- build K_ws [b][h][2064][64] bf16 --------------------------
__global__ __launch_bounds__(256) void fill_K(const unsigned short* __restrict__ qkv,
                                              const float* __restrict__ mem_k,
                                              unsigned short* __restrict__ Kw) {
  int tid = blockIdx.x * 256 + threadIdx.x;
  if (tid >= 2 * 16 * 2064 * 8) return;
  int d0 = (tid & 7) * 8;
  int j = (tid >> 3) % 2064;
  int h = ((tid >> 3) / 2064) & 15;
  int b = (tid >> 3) / (2064 * 16);
  S8U o;
  if (j < 16) {
    const float* s = mem_k + ((size_t)(h * 16 + j) * 64 + d0);
#pragma unroll
    for (int c = 0; c < 8; c++) o.u[c] = f2bf(s[c]);
  } else {
    o.v = *(const short8*)(qkv + (size_t)(b * 2048 + j - 16) * 3072 + 1024 + h * 64 + d0);
  }
  *(short8*)(Kw + ((size_t)(b * 16 + h) * 2064 + j) * 64 + d0) = o.v;
}

// ---------------- build Vt_ws [b][h][64][2064] bf16 (transposed) ------------
__global__ __launch_bounds__(256) void fill_Vt(const unsigned short* __restrict__ qkv,
                                               const float* __restrict__ mem_v,
                                               unsigned short* __restrict__ Vt) {
  __shared__ float sv[16][65];
  int jt = blockIdx.x, h = blockIdx.y, b = blockIdx.z;
  int t = threadIdx.x;
  int j = t >> 4, d0 = (t & 15) * 4;
  int jg = jt * 16 + j;
  float v0, v1, v2, v3;
  if (jg < 16) {
    const float* s = mem_v + ((size_t)(h * 16 + jg) * 64 + d0);
    v0 = s[0]; v1 = s[1]; v2 = s[2]; v3 = s[3];
  } else {
    const unsigned short* s = qkv + (size_t)(b * 2048 + jg - 16) * 3072 + 2048 + h * 64 + d0;
    v0 = bf2f(s[0]); v1 = bf2f(s[1]); v2 = bf2f(s[2]); v3 = bf2f(s[3]);
  }
  sv[j][d0 + 0] = v0; sv[j][d0 + 1] = v1; sv[j][d0 + 2] = v2; sv[j][d0 + 3] = v3;
  __syncthreads();
  int d = t >> 2, j4 = (t & 3) * 4;
  unsigned o0 = f2bf(sv[j4 + 0][d]) | ((unsigned)f2bf(sv[j4 + 1][d]) << 16);
  unsigned o1 = f2bf(sv[j4 + 2][d]) | ((unsigned)f2bf(sv[j4 + 3][d]) << 16);
  uint2 pk; pk.x = o0; pk.y = o1;
  *(uint2*)(Vt + ((size_t)(b * 16 + h) * 64 + d) * 2064 + jt * 16 + j4) = pk;
}

// ---------------------------------------------------------------------------
// attn_stats: l[b,i,k'] = sum over causal j of exp(S'[k',i,j]).
// Grid (c<13, it<32, b<2), 16 waves. i-tile 64, j-chunk 160, j-round 32.
// Dense S rows: addr = i*520 + j*16 + h; S = 66,560 B. 2-barrier round.
// Wave w: QK head h=w (all 64 i); pre-mix + exp for rows i* = 4w..4w+3.
// ---------------------------------------------------------------------------
__global__ __launch_bounds__(1024) void attn_stats(const unsigned short* __restrict__ qkv,
                                                   const unsigned short* __restrict__ Kw,
                                                   const float* __restrict__ pre,
                                                   float* __restrict__ l_ws) {
  const int c = blockIdx.x, it = blockIdx.y, b = blockIdx.z;
  const int i0 = it * 64;
  const int jmax = i0 + 80;          // exclusive causal bound (j <= i+16)
  const int jc0 = c * 160;
  if (jc0 >= jmax) return;
  const int jend = min(jmax, jc0 + 160);
  const int niter = (jend - jc0 + 31) >> 5;

  __shared__ unsigned short S_lds[64 * 520];  // 66,560 B

  const int tid = threadIdx.x, w = tid >> 6, lane = tid & 63;
  const int quad = lane >> 4, l16 = lane & 15;
  const int hoff = (quad < 2) ? quad * 8 : 0;

  short8 qa[4][2];
#pragma unroll
  for (int s = 0; s < 4; s++) {
    const unsigned short* p =
        qkv + (size_t)(b * 2048 + i0 + s * 16 + l16) * 3072 + w * 64 + quad * 8;
    qa[s][0] = *(const short8*)p;
    qa[s][1] = *(const short8*)(p + 32);
  }
  short8 preA;
#pragma unroll
  for (int jj = 0; jj < 8; jj++) {
    int h = quad * 8 + jj;
    preA[jj] = (short)((quad < 2) ? f2bf(pre[h * 16 + l16] * 0.125f) : 0);
  }
  const unsigned short* Kb = Kw + (size_t)(b * 16 + w) * 2064 * 64;

  float l_loc[4][4];
#pragma unroll
  for (int i4 = 0; i4 < 4; i4++)
#pragma unroll
    for (int r = 0; r < 4; r++) l_loc[i4][r] = 0.f;

  // K register prefetch: preload round 0
  short8 kf[2][2];
#pragma unroll
  for (int jt = 0; jt < 2; jt++) {
    int jr = min(jc0 + jt * 16 + l16, 2063);
    const unsigned short* kp = Kb + (size_t)jr * 64 + quad * 8;
    kf[jt][0] = *(const short8*)kp;
    kf[jt][1] = *(const short8*)(kp + 32);
  }

  for (int n = 0; n < niter; n++) {
    const int j0 = jc0 + n * 32;
    // ---- QK^T -> S_lds (bf16) ----
#pragma unroll
    for (int jt = 0; jt < 2; jt++)
#pragma unroll
      for (int s = 0; s < 4; s++) {
        floatx4 a = (floatx4){0.f, 0.f, 0.f, 0.f};
        a = MFMA16(qa[s][0], kf[jt][0], a);
        a = MFMA16(qa[s][1], kf[jt][1], a);
#pragma unroll
        for (int r = 0; r < 4; r++)
          S_lds[(s * 16 + quad * 4 + r) * 520 + (jt * 16 + l16) * 16 + w] = f2bf(a[r]);
      }
    // ---- prefetch next round's K (stays in flight across barriers) ----
    if (n + 1 < niter) {
      const int j0n = j0 + 32;
#pragma unroll
      for (int jt = 0; jt < 2; jt++) {
        int jr = min(j0n + jt * 16 + l16, 2063);
        const unsigned short* kp = Kb + (size_t)jr * 64 + quad * 8;
        kf[jt][0] = *(const short8*)kp;
        kf[jt][1] = *(const short8*)(kp + 32);
      }
    }
    BARLDS();
    // ---- pre-mix (16x16x32, zero-padded K) + exp accumulate ----
#pragma unroll
    for (int u = 0; u < 8; u++) {
      const int iloc = u >> 1, jt = u & 1, ii = w * 4 + iloc;
      const short8 bb = *(const short8*)(S_lds + ii * 520 + (jt * 16 + l16) * 16 + hoff);
      floatx4 sp = (floatx4){0.f, 0.f, 0.f, 0.f};
      sp = MFMA16(preA, bb, sp);
      const int jg = j0 + jt * 16 + l16;
      if (jg <= i0 + ii + 16) {
#pragma unroll
        for (int r = 0; r < 4; r++) l_loc[iloc][r] += __expf(sp[r]);
      }
    }
    if (n + 1 < niter) BARLDS();
  }
#pragma unroll
  for (int iloc = 0; iloc < 4; iloc++)
#pragma unroll
    for (int r = 0; r < 4; r++) {
      float v = l_loc[iloc][r];
      v += __shfl_xor(v, 1);
      v += __shfl_xor(v, 2);
      v += __shfl_xor(v, 4);
      v += __shfl_xor(v, 8);
      if (l16 == 0)
        atomicAdd(l_ws + ((size_t)(b * 2048 + i0 + w * 4 + iloc) * 16 + quad * 4 + r), v);
    }
}

// ---------------------------------------------------------------------------
// attn_av: recompute S', P=exp(S')/l, post-mix, AV; atomicAdd O_ws fp32.
// Grid (c<13, it<64, b<2), 16 waves, i-tile 32, j-chunk 160 (r4 best).
// FUSED premix->postmix via shfl (r8): P never touches LDS. Premix C-frag
// lane(quad,l16) reg r = P(k'=quad*4+r, j=l16); postmix B-frag needs
// lane(q,l16) to hold k'=q*8..q*8+7 at its j -> pack bf16 pairs, 4 __shfl
// from lanes quad*32+l16 / +16 (k'>=16 half zero-padded via postA).
// Dense S rows: S 33,280 B + Pp 41,216 B = 74,496 B. Wave w: QK head h=w;
// mixes rows i* = 2w..2w+1; AV value head k2=w. Plain launch_bounds(1024):
// allocator lands at 64 VGPR (r8); forcing min-waves spills (r7).
// ---------------------------------------------------------------------------
__global__ __launch_bounds__(1024) void attn_av(const unsigned short* __restrict__ qkv,
                                                const unsigned short* __restrict__ Kw,
                                                const unsigned short* __restrict__ Vt,
                                                const float* __restrict__ pre,
                                                const float* __restrict__ post,
                                                const float* __restrict__ l_ws,
                                                float* __restrict__ O_ws) {
  const int c = blockIdx.x, it = blockIdx.y, b = blockIdx.z;
  const int i0 = it * 32;
  const int jmax = i0 + 48;
  const int jc0 = c * 160;
  if (jc0 >= jmax) return;
  const int jend = min(jmax, jc0 + 160);
  const int niter = (jend - jc0 + 31) >> 5;

  __shared__ unsigned short S_lds[32 * 520];    // 33,280 B (QK output only)
  __shared__ unsigned short Pp_lds[16 * 1288];  // 41,216 B

  const int tid = threadIdx.x, w = tid >> 6, lane = tid & 63;
  const int quad = lane >> 4, l16 = lane & 15;
  const int hoff = (quad < 2) ? quad * 8 : 0;
  const int srcA = (quad * 32 + l16) & 63;      // shfl srcs for P regather
  const int srcB = (srcA + 16) & 63;

  short8 qa[2][2];
#pragma unroll
  for (int s = 0; s < 2; s++) {
    const unsigned short* p =
        qkv + (size_t)(b * 2048 + i0 + s * 16 + l16) * 3072 + w * 64 + quad * 8;
    qa[s][0] = *(const short8*)p;
    qa[s][1] = *(const short8*)(p + 32);
  }
  short8 preA, postA;
#pragma unroll
  for (int jj = 0; jj < 8; jj++) {
    int h = quad * 8 + jj;
    float pv = 0.f, qv = 0.f;
    if (quad < 2) { pv = pre[h * 16 + l16] * 0.125f; qv = post[h * 16 + l16]; }
    preA[jj] = (short)f2bf(pv);
    postA[jj] = (short)f2bf(qv);
  }
  float rl[2][4];
#pragma unroll
  for (int iloc = 0; iloc < 2; iloc++)
#pragma unroll
    for (int r = 0; r < 4; r++)
      rl[iloc][r] = 1.0f / l_ws[(size_t)(b * 2048 + i0 + w * 2 + iloc) * 16 + quad * 4 + r];

  floatx4 oacc[2][4];
#pragma unroll
  for (int g = 0; g < 2; g++)
#pragma unroll
    for (int d = 0; d < 4; d++) oacc[g][d] = (floatx4){0.f, 0.f, 0.f, 0.f};

  const unsigned short* Kb = Kw + (size_t)(b * 16 + w) * 2064 * 64;
  const unsigned short* Vb = Vt + (size_t)(b * 16 + w) * 64 * 2064;

  short8 kf[2][2];
#pragma unroll
  for (int jt = 0; jt < 2; jt++) {
    int jr = min(jc0 + jt * 16 + l16, 2063);
    const unsigned short* kp = Kb + (size_t)jr * 64 + quad * 8;
    kf[jt][0] = *(const short8*)kp;
    kf[jt][1] = *(const short8*)(kp + 32);
  }

  for (int n = 0; n < niter; n++) {
    const int j0 = jc0 + n * 32;
    // ---- V fragments for this iteration (independent; issues early) ----
    short8 vf[4];
    {
      const int jc = min(j0 + quad * 8, 2056);
#pragma unroll
      for (int d = 0; d < 4; d++)
        vf[d] = *(const short8*)(Vb + (size_t)(d * 16 + l16) * 2064 + jc);
    }
    // ---- QK^T -> S_lds ----
#pragma unroll
    for (int jt = 0; jt < 2; jt++)
#pragma unroll
      for (int s = 0; s < 2; s++) {
        floatx4 a = (floatx4){0.f, 0.f, 0.f, 0.f};
        a = MFMA16(qa[s][0], kf[jt][0], a);
        a = MFMA16(qa[s][1], kf[jt][1], a);
#pragma unroll
        for (int r = 0; r < 4; r++)
          S_lds[(s * 16 + quad * 4 + r) * 520 + (jt * 16 + l16) * 16 + w] = f2bf(a[r]);
      }
    // ---- prefetch next K ----
    if (n + 1 < niter) {
      const int j0n = j0 + 32;
#pragma unroll
      for (int jt = 0; jt < 2; jt++) {
        int jr = min(j0n + jt * 16 + l16, 2063);
        const unsigned short* kp = Kb + (size_t)jr * 64 + quad * 8;
        kf[jt][0] = *(const short8*)kp;
        kf[jt][1] = *(const short8*)(kp + 32);
      }
    }
    BARLDS();
    // ---- fused: pre-mix + exp/l -> P (regs) -> shfl regather -> post-mix ----
#pragma unroll
    for (int u = 0; u < 4; u++) {
      const int iloc = u >> 1, jt = u & 1, ii = w * 2 + iloc;
      const int sc = ii * 520 + (jt * 16 + l16) * 16;
      const short8 bb = *(const short8*)(S_lds + sc + hoff);
      floatx4 sp = (floatx4){0.f, 0.f, 0.f, 0.f};
      sp = MFMA16(preA, bb, sp);
      const int jg = j0 + jt * 16 + l16;
      const bool keep = jg <= (i0 + ii + 16);
      float p0 = keep ? __expf(sp[0]) * rl[iloc][0] : 0.f;
      float p1 = keep ? __expf(sp[1]) * rl[iloc][1] : 0.f;
      float p2 = keep ? __expf(sp[2]) * rl[iloc][2] : 0.f;
      float p3 = keep ? __expf(sp[3]) * rl[iloc][3] : 0.f;
      // pack P(k=quad*4+{0,1}) and (quad*4+{2,3}) as bf16 word-pairs
      unsigned w01 = (unsigned)f2bf(p0) | ((unsigned)f2bf(p1) << 16);
      unsigned w23 = (unsigned)f2bf(p2) | ((unsigned)f2bf(p3) << 16);
      // regather to postmix B-frag: lane (q,l16) needs k = q*8..q*8+7 at its j
      union { unsigned u32[4]; short8 v; } pfu;
      pfu.u32[0] = __shfl(w01, srcA, 64);
      pfu.u32[1] = __shfl(w23, srcA, 64);
      pfu.u32[2] = __shfl(w01, srcB, 64);
      pfu.u32[3] = __shfl(w23, srcB, 64);
      floatx4 pp = (floatx4){0.f, 0.f, 0.f, 0.f};
      pp = MFMA16(postA, pfu.v, pp);
#pragma unroll
      for (int r = 0; r < 4; r++)
        Pp_lds[(quad * 4 + r) * 1288 + ii * 40 + jt * 16 + l16] = f2bf(pp[r]);
    }
    BARLDS();
    // ---- AV: wave w = value head k2=w, K = 32 j's ----
#pragma unroll
    for (int g = 0; g < 2; g++) {
      const short8 paf = *(const short8*)(Pp_lds + w * 1288 + (g * 16 + l16) * 40 + quad * 8);
#pragma unroll
      for (int d = 0; d < 4; d++) oacc[g][d] = MFMA16(paf, vf[d], oacc[g][d]);
    }
  }
  // ---- accumulate into O_ws fp32 ----
#pragma unroll
  for (int g = 0; g < 2; g++)
#pragma unroll
    for (int d = 0; d < 4; d++)
#pragma unroll
      for (int r = 0; r < 4; r++)
        atomicAdd(O_ws + (size_t)(b * 2048 + i0 + g * 16 + quad * 4 + r) * 1024 +
                      w * 64 + d * 16 + l16,
                  oacc[g][d][r]);
}

// ---------------------------------------------------------------------------
extern "C" void kernel_launch(void* const* d_in, const int* in_sizes, int n_in,
                              void* d_out, int out_size, void* d_ws, size_t ws_size,
                              hipStream_t stream) {
  (void)in_sizes; (void)n_in; (void)out_size; (void)ws_size;
  const float* x     = (const float*)d_in[0];
  const float* Wq    = (const float*)d_in[1];
  const float* Wkv   = (const float*)d_in[2];
  const float* Wo    = (const float*)d_in[3];
  const float* pre   = (const float*)d_in[4];
  const float* post  = (const float*)d_in[5];
  const float* mem_k = (const float*)d_in[6];
  const float* mem_v = (const float*)d_in[7];
  float* out = (float*)d_out;
  char* ws = (char*)d_ws;

  // Temporally-aliased workspace (total 67,239,936 B):
  //   [0, 16.8M):  xb(8M)+WbT(6M)+pad — dead after qkv gemm -> O_ws fp32 16M
  //   [16.8M, 41.9M): qkv bf16 — dead after attn_av -> WoT (2M)
  //   [41.9M, 50.4M): Kw ; [50.4M, 58.9M): Vt
  //   [58.9M, 67.2M): l_ws (256K, dead after attn_av) then attn_b bf16 (8M)
  unsigned short* xb     = (unsigned short*)(ws);
  unsigned short* WbT    = (unsigned short*)(ws + 8388608);
  float*          O_ws   = (float*)(ws);                     // 16,777,216 B
  unsigned short* qkv    = (unsigned short*)(ws + 16777216); // 25,165,824 B
  unsigned short* WoT    = (unsigned short*)(ws + 16777216); // 2 MB (post-attn)
  unsigned short* Kw     = (unsigned short*)(ws + 41943040); //  8,454,144 B
  unsigned short* Vt     = (unsigned short*)(ws + 50397184); //  8,454,144 B
  float*          l_ws   = (float*)(ws + 58851328);          //    262,144 B
  unsigned short* attn_b = (unsigned short*)(ws + 58851328); //  8,388,608 B

  conv_bf16<<<2048, 256, 0, stream>>>(x, xb, 524288);
  transW<<<dim3(32, 32), 256, 0, stream>>>(Wq, 1024, WbT, 0);
  transW<<<dim3(64, 32), 256, 0, stream>>>(Wkv, 2048, WbT, 1024);
  gemm_bt<<<dim3(32, 24), 256, 0, stream>>>(xb, WbT, qkv, nullptr, 4096, 3072, 1024, 0);
  fill_K<<<2064, 256, 0, stream>>>(qkv, mem_k, Kw);
  fill_Vt<<<dim3(129, 16, 2), 256, 0, stream>>>(qkv, mem_v, Vt);
  hipMemsetAsync(O_ws, 0, 16777216, stream);   // xb/WbT dead now
  hipMemsetAsync(l_ws, 0, 262144, stream);
  attn_stats<<<dim3(13, 32, 2), 1024, 0, stream>>>(qkv, Kw, pre, l_ws);
  attn_av<<<dim3(13, 64, 2), 1024, 0, stream>>>(qkv, Kw, Vt, pre, post, l_ws, O_ws);
  conv_bf16<<<2048, 256, 0, stream>>>(O_ws, attn_b, 524288);  // l_ws dead now
  transW<<<dim3(32, 32), 256, 0, stream>>>(Wo, 1024, WoT, 0); // qkv dead now
  gemm_bt<<<dim3(32, 8), 256, 0, stream>>>(attn_b, WoT, nullptr, out, 4096, 1024, 1024, 1);
}